// Round 7
// baseline (198.130 us; speedup 1.0000x reference)
//
#include <hip/hip_runtime.h>

// Backward warp, bilinear sampling. B=16, H=W=1024 (pow2, hardcoded), C=3, fp32.
// R7: LDS-staged gathers. R5/R6 showed the TA/L1-request pipe is the limiter
// (~4.5 scattered line-requests/px). Block = 64x16 tile; stage image rows
// [h0-8,h0+24) x cols [w0-8,w0+72) into LDS via coalesced dwordx4 (10x fewer
// TA requests), gather from LDS (ds_read2_b32, stride-3 banks ~conflict-free).
// Rare out-of-window lanes (|flow|>~8) take the exact global fallback path.

struct __attribute__((packed, aligned(4))) R6 { float v[6]; };
typedef float f4 __attribute__((ext_vector_type(4), aligned(8)));
typedef float f2 __attribute__((ext_vector_type(2), aligned(8)));
typedef float f4u __attribute__((ext_vector_type(4), aligned(4)));

__global__ __launch_bounds__(256) void backwarp_kernel(
    const float* __restrict__ image,
    const float* __restrict__ flow,
    float* __restrict__ out) {
  constexpr int H = 1024, W = 1024;
  constexpr int NB = 16384;        // 16 batches * 16 tiles_x * 64 tiles_y
  constexpr int CHUNK = NB / 8;

  // LDS: 32 rows x 256 dwords (960B used, 1024B stride) = 32 KB
  __shared__ float lds[32 * 256];

  // XCD-chunked swizzle (16384 % 8 == 0 -> bijective), tile_y fastest so
  // vertically-adjacent tiles (sharing staged rows) land on the same XCD.
  int bid = blockIdx.x;
  int sb = (bid & 7) * CHUNK + (bid >> 3);
  int b      = sb >> 10;
  int r      = sb & 1023;
  int tile_x = r >> 6;             // [0,16)
  int tile_y = r & 63;             // [0,64)
  int w0t = tile_x << 6;
  int h0t = tile_y << 4;
  int plane = b << 20;
  int r_lo = h0t - 8;

  // ---- stage: 32 rows x 60 16B-chunks (padded to 64 for index math) ----
  // chunk k of row i covers global bytes ((plane+(gr<<10)+w0t-8)*12 + 16k ..+16)
  // left margin (8px*12B = 96B = 6 chunks) and right edge (54 chunks) align
  // exactly to 16B chunks, so per-chunk validity is a simple range test.
  int kmin = (tile_x == 0) ? 6 : 0;
  int khi  = (tile_x == 15) ? 54 : 60;
#pragma unroll
  for (int j = 0; j < 8; ++j) {
    int lin = threadIdx.x + (j << 8);   // [0,2048)
    int i = lin >> 6;                   // LDS row [0,32)
    int k = lin & 63;                   // 16B chunk
    int gr = r_lo + i;
    if (k >= kmin && k < khi && gr >= 0 && gr < H) {
      const char* src = (const char*)image +
          ((long long)(plane + (gr << 10) + w0t - 8) * 12) + (k << 4);
      f4u val = *reinterpret_cast<const f4u*>(src);
      *reinterpret_cast<f4*>((char*)lds + i * 1024 + (k << 4)) = val;
    }
  }
  __syncthreads();

  // ---- gather: 2x2 px per thread ----
  int qx = threadIdx.x & 31;
  int qy = threadIdx.x >> 5;
  int w0 = w0t + (qx << 1);
  int h0 = h0t + (qy << 1);

#pragma unroll
  for (int dy = 0; dy < 2; ++dy) {
    int h = h0 + dy;
    int idx0 = plane + (h << 10) + w0;   // even -> flow f4 16B-aligned
    f4 fl = __builtin_nontemporal_load(
        reinterpret_cast<const f4*>(flow + (size_t)idx0 * 2));
    float res[6];
#pragma unroll
    for (int dx = 0; dx < 2; ++dx) {
      float x = (float)(w0 + dx) + (dx ? fl.z : fl.x);
      float y = (float)h + (dx ? fl.w : fl.y);
      // faithful round-trip from the reference (x/1024 == x*(1/1024) exactly)
      x = 0.5f * (2.0f * (x * (1.0f / W) - 0.5f) + 1.0f) * W;
      y = 0.5f * (2.0f * (y * (1.0f / H) - 0.5f) + 1.0f) * H;

      int x0 = (int)x;             // trunc toward zero, like astype(int32)
      int y0 = (int)y;
      int x1 = x0 + 1;
      int y1 = y0 + 1;
      x0 = min(max(x0, 0), W - 1);
      x1 = min(max(x1, 0), W - 1);
      y0 = min(max(y0, 0), H - 1);
      y1 = min(max(y1, 0), H - 1);

      float wa = ((float)x1 - x) * ((float)y1 - y);
      float wb = ((float)x1 - x) * (y - (float)y0);
      float wc = (x - (float)x0) * ((float)y1 - y);
      float wd = (x - (float)x0) * (y - (float)y0);

      int bx = min(x0, W - 2);     // 6 contiguous floats cover {bx, bx+1}
      bool hiA = (x0 != bx);
      bool hiC = (x1 != bx);

      int ly0 = y0 - r_lo;
      int ly1 = y1 - r_lo;
      int lx  = bx - (w0t - 8);
      bool oob = ((unsigned)ly0 > 31u) | ((unsigned)ly1 > 31u) |
                 ((unsigned)lx > 78u);

      float a0, a1, a2, a3, a4, a5;   // row y0: 6 floats at bx
      float c0, c1, c2, c3, c4, c5;   // row y1
      if (!oob) {
        int d0 = (ly0 << 8) + lx * 3;
        int d1 = (ly1 << 8) + lx * 3;
        a0 = lds[d0];     a1 = lds[d0 + 1]; a2 = lds[d0 + 2];
        a3 = lds[d0 + 3]; a4 = lds[d0 + 4]; a5 = lds[d0 + 5];
        c0 = lds[d1];     c1 = lds[d1 + 1]; c2 = lds[d1 + 2];
        c3 = lds[d1 + 3]; c4 = lds[d1 + 4]; c5 = lds[d1 + 5];
      } else {            // exact global path for |flow| outliers
        const R6 g0 = *reinterpret_cast<const R6*>(
            image + (size_t)(plane + (y0 << 10) + bx) * 3);
        const R6 g1 = *reinterpret_cast<const R6*>(
            image + (size_t)(plane + (y1 << 10) + bx) * 3);
        a0 = g0.v[0]; a1 = g0.v[1]; a2 = g0.v[2];
        a3 = g0.v[3]; a4 = g0.v[4]; a5 = g0.v[5];
        c0 = g1.v[0]; c1 = g1.v[1]; c2 = g1.v[2];
        c3 = g1.v[3]; c4 = g1.v[4]; c5 = g1.v[5];
      }

      float pa0 = hiA ? a3 : a0, pa1 = hiA ? a4 : a1, pa2 = hiA ? a5 : a2;
      float pc0 = hiC ? a3 : a0, pc1 = hiC ? a4 : a1, pc2 = hiC ? a5 : a2;
      float pb0 = hiA ? c3 : c0, pb1 = hiA ? c4 : c1, pb2 = hiA ? c5 : c2;
      float pd0 = hiC ? c3 : c0, pd1 = hiC ? c4 : c1, pd2 = hiC ? c5 : c2;

      res[dx * 3 + 0] = wa * pa0 + wb * pb0 + wc * pc0 + wd * pd0;
      res[dx * 3 + 1] = wa * pa1 + wb * pb1 + wc * pc1 + wd * pd1;
      res[dx * 3 + 2] = wa * pa2 + wb * pb2 + wc * pc2 + wd * pd2;
    }
    float* o = out + (size_t)idx0 * 3;
    f4 s0 = {res[0], res[1], res[2], res[3]};
    f2 s1 = {res[4], res[5]};
    *reinterpret_cast<f4*>(o) = s0;
    *reinterpret_cast<f2*>(o + 4) = s1;
  }
}

extern "C" void kernel_launch(void* const* d_in, const int* in_sizes, int n_in,
                              void* d_out, int out_size, void* d_ws, size_t ws_size,
                              hipStream_t stream) {
  const float* image = (const float*)d_in[0];
  const float* flow  = (const float*)d_in[1];
  float* out = (float*)d_out;

  backwarp_kernel<<<16384, 256, 0, stream>>>(image, flow, out);
}

// Round 8
// 177.947 us; speedup vs baseline: 1.1134x; 1.1134x over previous
//
#include <hip/hip_runtime.h>

// Backward warp, bilinear sampling. B=16, H=W=1024 (pow2, hardcoded), C=3, fp32.
// R8: R5 structure + horizontal 1x2 px pairing ONLY (clean A/B vs R5):
//   - flow: one aligned float4 per 2 px (was 2x float2)
//   - out: nontemporal float4+float2 per 2 px (was 6 scalar stores)
//   - gathers: 4 independent fused 24B row-pair loads, issued back-to-back
// Wave = 128 px x 1 row (small vertical footprint; no per-thread dy chain).
// Tile = 128w x 4h per block; tile_y-fastest order + XCD-chunked swizzle.

struct __attribute__((packed, aligned(4))) R6 { float v[6]; };
typedef float f4 __attribute__((ext_vector_type(4), aligned(8)));
typedef float f2 __attribute__((ext_vector_type(2), aligned(8)));

__global__ __launch_bounds__(256) void backwarp_kernel(
    const float* __restrict__ image,
    const float* __restrict__ flow,
    float* __restrict__ out) {
  constexpr int H = 1024, W = 1024;
  constexpr int NB = 32768;        // 16 batches * 8 tiles_x * 256 tiles_y
  constexpr int CHUNK = NB / 8;

  // XCD-chunked swizzle (32768 % 8 == 0 -> bijective), tile_y fastest so
  // vertically-adjacent tiles (sharing gather rows) stay on one XCD.
  int bid = blockIdx.x;
  int sb = (bid & 7) * CHUNK + (bid >> 3);
  int b      = sb >> 11;           // 2048 blocks per batch
  int r      = sb & 2047;
  int tile_x = r >> 8;             // [0,8)
  int tile_y = r & 255;            // [0,256)

  int lane = threadIdx.x & 63;
  int wrow = threadIdx.x >> 6;     // [0,4)
  int w0 = (tile_x << 7) + (lane << 1);   // even
  int h  = (tile_y << 2) + wrow;
  int plane = b << 20;
  int idx0 = plane + (h << 10) + w0;

  // flow for both pixels: 16B aligned (idx0 even)
  f4 fl = *reinterpret_cast<const f4*>(flow + (size_t)idx0 * 2);

  float res[6];
#pragma unroll
  for (int dx = 0; dx < 2; ++dx) {
    float x = (float)(w0 + dx) + (dx ? fl.z : fl.x);
    float y = (float)h + (dx ? fl.w : fl.y);
    // faithful round-trip from the reference (x/1024 == x*(1/1024) exactly)
    x = 0.5f * (2.0f * (x * (1.0f / W) - 0.5f) + 1.0f) * W;
    y = 0.5f * (2.0f * (y * (1.0f / H) - 0.5f) + 1.0f) * H;

    int x0 = (int)x;               // trunc toward zero, like astype(int32)
    int y0 = (int)y;
    int x1 = x0 + 1;
    int y1 = y0 + 1;
    x0 = min(max(x0, 0), W - 1);
    x1 = min(max(x1, 0), W - 1);
    y0 = min(max(y0, 0), H - 1);
    y1 = min(max(y1, 0), H - 1);

    float wa = ((float)x1 - x) * ((float)y1 - y);
    float wb = ((float)x1 - x) * (y - (float)y0);
    float wc = (x - (float)x0) * ((float)y1 - y);
    float wd = (x - (float)x0) * (y - (float)y0);

    // Fused gather: 6 contiguous floats at bx cover pixels {bx, bx+1};
    // select halves for (x0, x1) including all border-clamp cases.
    int bx = min(x0, W - 2);       // keep the 6-float load in-bounds of the row
    bool hiA = (x0 != bx);         // pa lives in v[3..5]
    bool hiC = (x1 != bx);         // pc lives in v[3..5]

    const R6 r0 = *reinterpret_cast<const R6*>(image + (size_t)(plane + (y0 << 10) + bx) * 3);
    const R6 r1 = *reinterpret_cast<const R6*>(image + (size_t)(plane + (y1 << 10) + bx) * 3);

#pragma unroll
    for (int c = 0; c < 3; ++c) {
      float pa  = hiA ? r0.v[3 + c] : r0.v[c];
      float pc_ = hiC ? r0.v[3 + c] : r0.v[c];
      float pb  = hiA ? r1.v[3 + c] : r1.v[c];
      float pd  = hiC ? r1.v[3 + c] : r1.v[c];
      res[dx * 3 + c] = wa * pa + wb * pb + wc * pc_ + wd * pd;
    }
  }

  // 2 px = 24B contiguous; NT (out is never re-read; keep L2/L3 for image)
  float* o = out + (size_t)idx0 * 3;
  f4 s0 = {res[0], res[1], res[2], res[3]};
  f2 s1 = {res[4], res[5]};
  __builtin_nontemporal_store(s0, reinterpret_cast<f4*>(o));
  __builtin_nontemporal_store(s1, reinterpret_cast<f2*>(o + 4));
}

extern "C" void kernel_launch(void* const* d_in, const int* in_sizes, int n_in,
                              void* d_out, int out_size, void* d_ws, size_t ws_size,
                              hipStream_t stream) {
  const float* image = (const float*)d_in[0];
  const float* flow  = (const float*)d_in[1];
  float* out = (float*)d_out;

  backwarp_kernel<<<32768, 256, 0, stream>>>(image, flow, out);
}